// Round 4
// baseline (1449.765 us; speedup 1.0000x reference)
//
#include <hip/hip_runtime.h>

// NodeModel: agg = segment_sum(x[row], col); h = concat(x, agg); out = MLP(h).
//
// Fast path: counting-sort edges by key = (col>>12)*G + (row>>17):
// col-bucket major (4096-node LDS accumulator tiles), row-group minor
// (128K-node x-windows -> L2-resident gathers). Packed payload is
// (row<<12)|(col&4095), exact u32 for N <= 2^20. bucket_agg consumes each
// col-bucket's G contiguous segments and applies the node MLP in-epilogue.
// Fallback (ws too small / N too big): global atomicAdd + separate MLP.

#define CSHIFT 12
#define BSIZE  4096           // nodes per col-bucket
#define RSHIFT 17             // 128K nodes per row-group (1.5 MB of x)
#define MAXKEYS 4096
#define NBLK   128            // edge chunks for hist/scatter
#define AGG_THREADS 1024

// ---------------- fast path kernels ----------------

__global__ __launch_bounds__(256) void hist_kernel(
    const int* __restrict__ rows, const int* __restrict__ cols,
    int* __restrict__ hist, int nkeys, int G, int chunk, int n_edges)
{
    __shared__ int lh[MAXKEYS];
    const int t = threadIdx.x, b = blockIdx.x;
    for (int k = t; k < nkeys; k += 256) lh[k] = 0;
    __syncthreads();

    long long s = (long long)b * chunk;
    long long e = s + chunk; if (e > n_edges) e = n_edges;
    if (s < e) {
        const int n = (int)(e - s);
        const int n4 = n >> 2;
        const int4* __restrict__ c4p = reinterpret_cast<const int4*>(cols + s);
        const int4* __restrict__ r4p = reinterpret_cast<const int4*>(rows + s);
        for (int i = t; i < n4; i += 256) {
            int4 c = c4p[i];
            int4 r = r4p[i];
            atomicAdd(&lh[((unsigned)c.x >> CSHIFT) * G + ((unsigned)r.x >> RSHIFT)], 1);
            atomicAdd(&lh[((unsigned)c.y >> CSHIFT) * G + ((unsigned)r.y >> RSHIFT)], 1);
            atomicAdd(&lh[((unsigned)c.z >> CSHIFT) * G + ((unsigned)r.z >> RSHIFT)], 1);
            atomicAdd(&lh[((unsigned)c.w >> CSHIFT) * G + ((unsigned)r.w >> RSHIFT)], 1);
        }
        for (int i = (n4 << 2) + t; i < n; i += 256) {
            int c = cols[s + i], r = rows[s + i];
            atomicAdd(&lh[((unsigned)c >> CSHIFT) * G + ((unsigned)r >> RSHIFT)], 1);
        }
    }
    __syncthreads();
    for (int k = t; k < nkeys; k += 256) hist[(size_t)b * nkeys + k] = lh[k];
}

// For each key k: exclusive-scan hist[b][k] along b; keyTotal[k] = total.
__global__ __launch_bounds__(NBLK) void scan_blocks_kernel(
    int* __restrict__ hist, int* __restrict__ keyTotal, int nkeys)
{
    __shared__ int sd[NBLK];
    const int t = threadIdx.x, k = blockIdx.x;
    const int v = hist[(size_t)t * nkeys + k];
    sd[t] = v; __syncthreads();
#pragma unroll
    for (int off = 1; off < NBLK; off <<= 1) {
        int a = (t >= off) ? sd[t - off] : 0;
        __syncthreads();
        sd[t] += a;
        __syncthreads();
    }
    hist[(size_t)t * nkeys + k] = sd[t] - v;   // exclusive along b
    if (t == NBLK - 1) keyTotal[k] = sd[t];
}

// Exclusive scan of keyTotal -> keyStart[0..nkeys] (2 elems/thread, nkeys<=2048).
__global__ __launch_bounds__(1024) void scan_keys_kernel(
    const int* __restrict__ keyTotal, int* __restrict__ keyStart, int nkeys)
{
    __shared__ int sd[1024];
    const int t = threadIdx.x;
    const int i0 = 2 * t, i1 = 2 * t + 1;
    const int v0 = (i0 < nkeys) ? keyTotal[i0] : 0;
    const int v1 = (i1 < nkeys) ? keyTotal[i1] : 0;
    sd[t] = v0 + v1; __syncthreads();
#pragma unroll
    for (int off = 1; off < 1024; off <<= 1) {
        int a = (t >= off) ? sd[t - off] : 0;
        __syncthreads();
        sd[t] += a;
        __syncthreads();
    }
    const int base = sd[t] - (v0 + v1);
    if (i0 < nkeys) keyStart[i0] = base;
    if (i1 < nkeys) keyStart[i1] = base + v0;
    if (t == 1023) keyStart[nkeys] = sd[1023];
}

__global__ __launch_bounds__(256) void scatter_kernel(
    const int* __restrict__ rows, const int* __restrict__ cols,
    const int* __restrict__ hist, const int* __restrict__ keyStart,
    unsigned* __restrict__ packed, int nkeys, int G, int chunk, int n_edges)
{
    __shared__ int lc[MAXKEYS];
    const int t = threadIdx.x, b = blockIdx.x;
    for (int k = t; k < nkeys; k += 256)
        lc[k] = keyStart[k] + hist[(size_t)b * nkeys + k];
    __syncthreads();

    long long s = (long long)b * chunk;
    long long e = s + chunk; if (e > n_edges) e = n_edges;
    if (s < e) {
        const int n = (int)(e - s);
        const int n4 = n >> 2;
        const int4* __restrict__ c4p = reinterpret_cast<const int4*>(cols + s);
        const int4* __restrict__ r4p = reinterpret_cast<const int4*>(rows + s);
        for (int i = t; i < n4; i += 256) {
            int4 c = c4p[i];
            int4 r = r4p[i];
            int p;
            p = atomicAdd(&lc[((unsigned)c.x >> CSHIFT) * G + ((unsigned)r.x >> RSHIFT)], 1);
            packed[p] = ((unsigned)r.x << CSHIFT) | ((unsigned)c.x & (BSIZE - 1));
            p = atomicAdd(&lc[((unsigned)c.y >> CSHIFT) * G + ((unsigned)r.y >> RSHIFT)], 1);
            packed[p] = ((unsigned)r.y << CSHIFT) | ((unsigned)c.y & (BSIZE - 1));
            p = atomicAdd(&lc[((unsigned)c.z >> CSHIFT) * G + ((unsigned)r.z >> RSHIFT)], 1);
            packed[p] = ((unsigned)r.z << CSHIFT) | ((unsigned)c.z & (BSIZE - 1));
            p = atomicAdd(&lc[((unsigned)c.w >> CSHIFT) * G + ((unsigned)r.w >> RSHIFT)], 1);
            packed[p] = ((unsigned)r.w << CSHIFT) | ((unsigned)c.w & (BSIZE - 1));
        }
        for (int i = (n4 << 2) + t; i < n; i += 256) {
            int c = cols[s + i], r = rows[s + i];
            int p = atomicAdd(&lc[((unsigned)c >> CSHIFT) * G + ((unsigned)r >> RSHIFT)], 1);
            packed[p] = ((unsigned)r << CSHIFT) | ((unsigned)c & (BSIZE - 1));
        }
    }
}

// One block per col-bucket: LDS-accumulate its G contiguous row-group
// segments, then apply the node MLP in the epilogue and write final out.
__global__ __launch_bounds__(AGG_THREADS) void bucket_agg_mlp_kernel(
    const unsigned* __restrict__ packed, const float* __restrict__ x,
    const int* __restrict__ keyStart,
    const float* __restrict__ W1, const float* __restrict__ b1,
    const float* __restrict__ W2, const float* __restrict__ b2,
    const float* __restrict__ W3, const float* __restrict__ b3,
    float* __restrict__ out, int n_nodes, int G)
{
    __shared__ float acc[BSIZE * 3];   // 48 KB
    __shared__ float sW1[96], sb1[16], sW2[256], sb2[16], sW3[48], sb3[3];
    const int t = threadIdx.x, k = blockIdx.x;

    if (t < 96)  sW1[t] = W1[t];
    if (t < 16)  sb1[t] = b1[t];
    if (t < 256) sW2[t] = W2[t];
    if (t >= 256 && t < 272) sb2[t - 256] = b2[t - 256];
    if (t >= 272 && t < 320) sW3[t - 272] = W3[t - 272];
    if (t >= 320 && t < 323) sb3[t - 320] = b3[t - 320];
    for (int f = t; f < BSIZE * 3; f += AGG_THREADS) acc[f] = 0.0f;
    __syncthreads();

    const int s = keyStart[k * G];
    const int e = keyStart[k * G + G];

    int i = s + t;
    for (; i + 3 * AGG_THREADS < e; i += 4 * AGG_THREADS) {
        unsigned p0 = packed[i];
        unsigned p1 = packed[i + AGG_THREADS];
        unsigned p2 = packed[i + 2 * AGG_THREADS];
        unsigned p3 = packed[i + 3 * AGG_THREADS];
        const float* xs0 = x + 3ll * (p0 >> CSHIFT);
        const float* xs1 = x + 3ll * (p1 >> CSHIFT);
        const float* xs2 = x + 3ll * (p2 >> CSHIFT);
        const float* xs3 = x + 3ll * (p3 >> CSHIFT);
        float a0 = xs0[0], b0 = xs0[1], c0 = xs0[2];
        float a1 = xs1[0], b1v = xs1[1], c1 = xs1[2];
        float a2 = xs2[0], b2v = xs2[1], c2 = xs2[2];
        float a3 = xs3[0], b3v = xs3[1], c3 = xs3[2];
        int j0 = (int)(p0 & (BSIZE - 1)) * 3;
        int j1 = (int)(p1 & (BSIZE - 1)) * 3;
        int j2 = (int)(p2 & (BSIZE - 1)) * 3;
        int j3 = (int)(p3 & (BSIZE - 1)) * 3;
        atomicAdd(&acc[j0 + 0], a0); atomicAdd(&acc[j0 + 1], b0);  atomicAdd(&acc[j0 + 2], c0);
        atomicAdd(&acc[j1 + 0], a1); atomicAdd(&acc[j1 + 1], b1v); atomicAdd(&acc[j1 + 2], c1);
        atomicAdd(&acc[j2 + 0], a2); atomicAdd(&acc[j2 + 1], b2v); atomicAdd(&acc[j2 + 2], c2);
        atomicAdd(&acc[j3 + 0], a3); atomicAdd(&acc[j3 + 1], b3v); atomicAdd(&acc[j3 + 2], c3);
    }
    for (; i < e; i += AGG_THREADS) {
        const unsigned p = packed[i];
        const float* __restrict__ xs = x + 3ll * (p >> CSHIFT);
        const int j = (int)(p & (BSIZE - 1)) * 3;
        atomicAdd(&acc[j + 0], xs[0]);
        atomicAdd(&acc[j + 1], xs[1]);
        atomicAdd(&acc[j + 2], xs[2]);
    }
    __syncthreads();

    // ---- fused node MLP over this bucket's nodes ----
    const long long base = (long long)k << CSHIFT;
    long long lim = (long long)n_nodes - base;
    if (lim > BSIZE) lim = BSIZE;
    if (lim <= 0) return;

    for (int j = t; j < (int)lim; j += AGG_THREADS) {
        const long long node = base + j;
        float in6[6];
        in6[0] = x[3 * node + 0];
        in6[1] = x[3 * node + 1];
        in6[2] = x[3 * node + 2];
        in6[3] = acc[3 * j + 0];
        in6[4] = acc[3 * j + 1];
        in6[5] = acc[3 * j + 2];

        float h1[16];
#pragma unroll
        for (int q = 0; q < 16; ++q) {
            float sv = sb1[q];
#pragma unroll
            for (int r = 0; r < 6; ++r) sv = fmaf(in6[r], sW1[r * 16 + q], sv);
            h1[q] = fmaxf(sv, 0.0f);
        }
        float h2[16];
#pragma unroll
        for (int q = 0; q < 16; ++q) {
            float sv = sb2[q];
#pragma unroll
            for (int r = 0; r < 16; ++r) sv = fmaf(h1[r], sW2[r * 16 + q], sv);
            h2[q] = fmaxf(sv, 0.0f);
        }
        float o0 = sb3[0], o1 = sb3[1], o2 = sb3[2];
#pragma unroll
        for (int q = 0; q < 16; ++q) {
            o0 = fmaf(h2[q], sW3[q * 3 + 0], o0);
            o1 = fmaf(h2[q], sW3[q * 3 + 1], o1);
            o2 = fmaf(h2[q], sW3[q * 3 + 2], o2);
        }
        out[3 * node + 0] = o0;
        out[3 * node + 1] = o1;
        out[3 * node + 2] = o2;
    }
}

// ---------------- fallback (global atomics) ----------------

__global__ __launch_bounds__(256) void edge_scatter_kernel(
    const int* __restrict__ rows, const int* __restrict__ cols,
    const float* __restrict__ x, float* __restrict__ agg, int n_edges)
{
    const long long tid = (long long)blockIdx.x * blockDim.x + threadIdx.x;
    const long long stride = (long long)gridDim.x * blockDim.x;
    for (long long i = tid; i < n_edges; i += stride) {
        int r = rows[i], c = cols[i];
        const float* xs = x + 3ll * r; float* a = agg + 3ll * c;
        atomicAdd(a + 0, xs[0]); atomicAdd(a + 1, xs[1]); atomicAdd(a + 2, xs[2]);
    }
}

__global__ __launch_bounds__(256) void node_mlp_kernel(
    const float* __restrict__ x,
    const float* __restrict__ W1, const float* __restrict__ b1,
    const float* __restrict__ W2, const float* __restrict__ b2,
    const float* __restrict__ W3, const float* __restrict__ b3,
    float* __restrict__ out, int n_nodes)
{
    __shared__ float sW1[96], sb1[16], sW2[256], sb2[16], sW3[48], sb3[3];
    const int t = threadIdx.x;
    if (t < 96)  sW1[t] = W1[t];
    if (t < 16)  sb1[t] = b1[t];
    sW2[t] = W2[t];
    if (t < 16)  sb2[t] = b2[t];
    if (t < 48)  sW3[t] = W3[t];
    if (t < 3)   sb3[t] = b3[t];
    __syncthreads();

    const int i = blockIdx.x * 256 + t;
    if (i >= n_nodes) return;

    float in6[6];
    in6[0] = x[3 * i + 0];
    in6[1] = x[3 * i + 1];
    in6[2] = x[3 * i + 2];
    in6[3] = out[3 * i + 0];
    in6[4] = out[3 * i + 1];
    in6[5] = out[3 * i + 2];

    float h1[16];
#pragma unroll
    for (int j = 0; j < 16; ++j) {
        float s = sb1[j];
#pragma unroll
        for (int k = 0; k < 6; ++k) s = fmaf(in6[k], sW1[k * 16 + j], s);
        h1[j] = fmaxf(s, 0.0f);
    }
    float h2[16];
#pragma unroll
    for (int j = 0; j < 16; ++j) {
        float s = sb2[j];
#pragma unroll
        for (int k = 0; k < 16; ++k) s = fmaf(h1[k], sW2[k * 16 + j], s);
        h2[j] = fmaxf(s, 0.0f);
    }
    float o[3];
#pragma unroll
    for (int c = 0; c < 3; ++c) {
        float s = sb3[c];
#pragma unroll
        for (int j = 0; j < 16; ++j) s = fmaf(h2[j], sW3[j * 3 + c], s);
        o[c] = s;
    }
    out[3 * i + 0] = o[0];
    out[3 * i + 1] = o[1];
    out[3 * i + 2] = o[2];
}

extern "C" void kernel_launch(void* const* d_in, const int* in_sizes, int n_in,
                              void* d_out, int out_size, void* d_ws, size_t ws_size,
                              hipStream_t stream) {
    const float* x   = (const float*)d_in[0];
    const int*   ei  = (const int*)d_in[1];   // [2, E] int32
    const float* W1  = (const float*)d_in[5];
    const float* b1  = (const float*)d_in[6];
    const float* W2  = (const float*)d_in[7];
    const float* b2  = (const float*)d_in[8];
    const float* W3  = (const float*)d_in[9];
    const float* b3  = (const float*)d_in[10];

    const int n_nodes = in_sizes[0] / 3;
    const int n_edges = in_sizes[1] / 2;
    const int* rows = ei;            // edge_index[0]
    const int* cols = ei + n_edges;  // edge_index[1]
    float* out = (float*)d_out;

    const int nb = (n_nodes + BSIZE - 1) >> CSHIFT;          // col-buckets
    const int G  = (n_nodes + (1 << RSHIFT) - 1) >> RSHIFT;  // row-groups
    const int nkeys = nb * G;

    // ws layout: packed[E] u32 | hist[NBLK*nkeys] i32 | keyTotal[nkeys] | keyStart[nkeys+1]
    const size_t need = (size_t)n_edges * 4 + (size_t)NBLK * nkeys * 4
                      + (size_t)nkeys * 4 + (size_t)(nkeys + 1) * 4;
    const bool fast = (ws_size >= need) && (nkeys <= MAXKEYS) && (nkeys <= 2048)
                   && (n_nodes <= (1 << 20));   // (row<<12)|local fits u32

    if (fast) {
        unsigned* packed = (unsigned*)d_ws;
        int* hist        = (int*)(packed + n_edges);
        int* keyTotal    = hist + (size_t)NBLK * nkeys;
        int* keyStart    = keyTotal + nkeys;

        int chunk = (n_edges + NBLK - 1) / NBLK;
        chunk = (chunk + 3) & ~3;    // keep per-block int4 loads 16B-aligned

        hist_kernel<<<NBLK, 256, 0, stream>>>(rows, cols, hist, nkeys, G, chunk, n_edges);
        scan_blocks_kernel<<<nkeys, NBLK, 0, stream>>>(hist, keyTotal, nkeys);
        scan_keys_kernel<<<1, 1024, 0, stream>>>(keyTotal, keyStart, nkeys);
        scatter_kernel<<<NBLK, 256, 0, stream>>>(rows, cols, hist, keyStart,
                                                 packed, nkeys, G, chunk, n_edges);
        bucket_agg_mlp_kernel<<<nb, AGG_THREADS, 0, stream>>>(
            packed, x, keyStart, W1, b1, W2, b2, W3, b3, out, n_nodes, G);
    } else {
        hipMemsetAsync(d_out, 0, (size_t)out_size * sizeof(float), stream);
        edge_scatter_kernel<<<8192, 256, 0, stream>>>(rows, cols, x, out, n_edges);
        const int nblocks = (n_nodes + 255) / 256;
        node_mlp_kernel<<<nblocks, 256, 0, stream>>>(x, W1, b1, W2, b2, W3, b3, out, n_nodes);
    }
}

// Round 5
// 898.360 us; speedup vs baseline: 1.6138x; 1.6138x over previous
//
#include <hip/hip_runtime.h>

// NodeModel: agg = segment_sum(x[row], col); h = concat(x, agg); out = MLP(h).
//
// Fast path: single counting-sort by col-bucket (col>>12, 245 keys -- the
// proven write-combining-safe cursor count). Payload (row<<12)|col_local
// carries the row-group in its top 3 bits. bucket_agg makes 8 sweeps over
// its segment filtered by row-group: all blocks sweep the same 1.5 MB
// x-window in phase -> gathers are L2 hits (kills the miss-queue latency
// bound of the unsorted gather). MLP fused into the agg epilogue.
// Fallback (ws too small / N too big): global atomicAdd + separate MLP.

#define CSHIFT 12
#define BSIZE  4096           // nodes per col-bucket (48 KB LDS acc)
#define RSHIFT 17             // 128K-node row-window (1.5 MB of x) per sweep
#define NSWEEP 8
#define MAXNB  2048
#define NBLK   512            // edge chunks for hist/scatter (245-cursor-safe)
#define HS_THREADS 1024       // hist/scatter block size
#define AGG_THREADS 1024

// ---------------- fast path kernels ----------------

__global__ __launch_bounds__(HS_THREADS) void hist_kernel(
    const int* __restrict__ cols, int* __restrict__ hist,
    int nb, int chunk, int n_edges)
{
    __shared__ int lh[MAXNB];
    const int t = threadIdx.x, b = blockIdx.x;
    for (int k = t; k < nb; k += HS_THREADS) lh[k] = 0;
    __syncthreads();

    long long s = (long long)b * chunk;
    long long e = s + chunk; if (e > n_edges) e = n_edges;
    if (s < e) {
        const int n = (int)(e - s);
        const int n4 = n >> 2;
        const int4* __restrict__ c4p = reinterpret_cast<const int4*>(cols + s);
        for (int i = t; i < n4; i += HS_THREADS) {
            int4 c = c4p[i];
            atomicAdd(&lh[(unsigned)c.x >> CSHIFT], 1);
            atomicAdd(&lh[(unsigned)c.y >> CSHIFT], 1);
            atomicAdd(&lh[(unsigned)c.z >> CSHIFT], 1);
            atomicAdd(&lh[(unsigned)c.w >> CSHIFT], 1);
        }
        for (int i = (n4 << 2) + t; i < n; i += HS_THREADS)
            atomicAdd(&lh[(unsigned)cols[s + i] >> CSHIFT], 1);
    }
    __syncthreads();
    for (int k = t; k < nb; k += HS_THREADS) hist[(size_t)b * nb + k] = lh[k];
}

// For each key k: exclusive-scan hist[b][k] along b; keyTotal[k] = total.
__global__ __launch_bounds__(NBLK) void scan_blocks_kernel(
    int* __restrict__ hist, int* __restrict__ keyTotal, int nb)
{
    __shared__ int sd[NBLK];
    const int t = threadIdx.x, k = blockIdx.x;
    const int v = hist[(size_t)t * nb + k];
    sd[t] = v; __syncthreads();
#pragma unroll
    for (int off = 1; off < NBLK; off <<= 1) {
        int a = (t >= off) ? sd[t - off] : 0;
        __syncthreads();
        sd[t] += a;
        __syncthreads();
    }
    hist[(size_t)t * nb + k] = sd[t] - v;   // exclusive along b
    if (t == NBLK - 1) keyTotal[k] = sd[t];
}

// Exclusive scan of keyTotal -> keyStart[0..nb] (2 elems/thread, nb<=2048).
__global__ __launch_bounds__(1024) void scan_keys_kernel(
    const int* __restrict__ keyTotal, int* __restrict__ keyStart, int nb)
{
    __shared__ int sd[1024];
    const int t = threadIdx.x;
    const int i0 = 2 * t, i1 = 2 * t + 1;
    const int v0 = (i0 < nb) ? keyTotal[i0] : 0;
    const int v1 = (i1 < nb) ? keyTotal[i1] : 0;
    sd[t] = v0 + v1; __syncthreads();
#pragma unroll
    for (int off = 1; off < 1024; off <<= 1) {
        int a = (t >= off) ? sd[t - off] : 0;
        __syncthreads();
        sd[t] += a;
        __syncthreads();
    }
    const int base = sd[t] - (v0 + v1);
    if (i0 < nb) keyStart[i0] = base;
    if (i1 < nb) keyStart[i1] = base + v0;
    if (t == 1023) keyStart[nb] = sd[1023];
}

__global__ __launch_bounds__(HS_THREADS) void scatter_kernel(
    const int* __restrict__ rows, const int* __restrict__ cols,
    const int* __restrict__ hist, const int* __restrict__ keyStart,
    unsigned* __restrict__ packed, int nb, int chunk, int n_edges)
{
    __shared__ int lc[MAXNB];
    const int t = threadIdx.x, b = blockIdx.x;
    for (int k = t; k < nb; k += HS_THREADS)
        lc[k] = keyStart[k] + hist[(size_t)b * nb + k];
    __syncthreads();

    long long s = (long long)b * chunk;
    long long e = s + chunk; if (e > n_edges) e = n_edges;
    if (s < e) {
        const int n = (int)(e - s);
        const int n4 = n >> 2;
        const int4* __restrict__ c4p = reinterpret_cast<const int4*>(cols + s);
        const int4* __restrict__ r4p = reinterpret_cast<const int4*>(rows + s);
        for (int i = t; i < n4; i += HS_THREADS) {
            int4 c = c4p[i];
            int4 r = r4p[i];
            int p;
            p = atomicAdd(&lc[(unsigned)c.x >> CSHIFT], 1);
            packed[p] = ((unsigned)r.x << CSHIFT) | ((unsigned)c.x & (BSIZE - 1));
            p = atomicAdd(&lc[(unsigned)c.y >> CSHIFT], 1);
            packed[p] = ((unsigned)r.y << CSHIFT) | ((unsigned)c.y & (BSIZE - 1));
            p = atomicAdd(&lc[(unsigned)c.z >> CSHIFT], 1);
            packed[p] = ((unsigned)r.z << CSHIFT) | ((unsigned)c.z & (BSIZE - 1));
            p = atomicAdd(&lc[(unsigned)c.w >> CSHIFT], 1);
            packed[p] = ((unsigned)r.w << CSHIFT) | ((unsigned)c.w & (BSIZE - 1));
        }
        for (int i = (n4 << 2) + t; i < n; i += HS_THREADS) {
            int c = cols[s + i], r = rows[s + i];
            int p = atomicAdd(&lc[(unsigned)c >> CSHIFT], 1);
            packed[p] = ((unsigned)r << CSHIFT) | ((unsigned)c & (BSIZE - 1));
        }
    }
}

// One block per col-bucket. 8 row-window sweeps over the segment: only
// edges with p>>29 == sweep are gathered -> x window is L2-resident.
// Node MLP fused in the epilogue.
__global__ __launch_bounds__(AGG_THREADS) void bucket_agg_mlp_kernel(
    const unsigned* __restrict__ packed, const float* __restrict__ x,
    const int* __restrict__ keyStart,
    const float* __restrict__ W1, const float* __restrict__ b1,
    const float* __restrict__ W2, const float* __restrict__ b2,
    const float* __restrict__ W3, const float* __restrict__ b3,
    float* __restrict__ out, int n_nodes)
{
    __shared__ float acc[BSIZE * 3];   // 48 KB
    __shared__ float sW1[96], sb1[16], sW2[256], sb2[16], sW3[48], sb3[3];
    const int t = threadIdx.x, k = blockIdx.x;

    if (t < 96)  sW1[t] = W1[t];
    if (t < 16)  sb1[t] = b1[t];
    if (t < 256) sW2[t] = W2[t];
    if (t >= 256 && t < 272) sb2[t - 256] = b2[t - 256];
    if (t >= 272 && t < 320) sW3[t - 272] = W3[t - 272];
    if (t >= 320 && t < 323) sb3[t - 320] = b3[t - 320];
    for (int f = t; f < BSIZE * 3; f += AGG_THREADS) acc[f] = 0.0f;
    __syncthreads();

    const int s = keyStart[k];
    const int e = keyStart[k + 1];
    int s4 = (s + 3) & ~3; if (s4 > e) s4 = e;
    const int e4 = s4 + ((e - s4) & ~3);
    const uint4* __restrict__ packed4 = reinterpret_cast<const uint4*>(packed);

    auto maybe_acc = [&](unsigned p, unsigned g) {
        if ((p >> (CSHIFT + RSHIFT)) == g) {
            const float* __restrict__ xs = x + 3ll * (p >> CSHIFT);
            const int j = (int)(p & (BSIZE - 1)) * 3;
            float v0 = xs[0], v1 = xs[1], v2 = xs[2];
            atomicAdd(&acc[j + 0], v0);
            atomicAdd(&acc[j + 1], v1);
            atomicAdd(&acc[j + 2], v2);
        }
    };

    for (unsigned g = 0; g < NSWEEP; ++g) {
        // ragged head + tail (<=3 each), filtered by g like the main loop
        for (int i = s + t; i < s4; i += AGG_THREADS) maybe_acc(packed[i], g);
        for (int i = e4 + t; i < e; i += AGG_THREADS) maybe_acc(packed[i], g);
        for (int i = (s4 >> 2) + t; i < (e4 >> 2); i += AGG_THREADS) {
            uint4 p4 = packed4[i];
            maybe_acc(p4.x, g);
            maybe_acc(p4.y, g);
            maybe_acc(p4.z, g);
            maybe_acc(p4.w, g);
        }
    }
    __syncthreads();

    // ---- fused node MLP over this bucket's nodes ----
    const long long base = (long long)k << CSHIFT;
    long long lim = (long long)n_nodes - base;
    if (lim > BSIZE) lim = BSIZE;
    if (lim <= 0) return;

    for (int j = t; j < (int)lim; j += AGG_THREADS) {
        const long long node = base + j;
        float in6[6];
        in6[0] = x[3 * node + 0];
        in6[1] = x[3 * node + 1];
        in6[2] = x[3 * node + 2];
        in6[3] = acc[3 * j + 0];
        in6[4] = acc[3 * j + 1];
        in6[5] = acc[3 * j + 2];

        float h1[16];
#pragma unroll
        for (int q = 0; q < 16; ++q) {
            float sv = sb1[q];
#pragma unroll
            for (int r = 0; r < 6; ++r) sv = fmaf(in6[r], sW1[r * 16 + q], sv);
            h1[q] = fmaxf(sv, 0.0f);
        }
        float h2[16];
#pragma unroll
        for (int q = 0; q < 16; ++q) {
            float sv = sb2[q];
#pragma unroll
            for (int r = 0; r < 16; ++r) sv = fmaf(h1[r], sW2[r * 16 + q], sv);
            h2[q] = fmaxf(sv, 0.0f);
        }
        float o0 = sb3[0], o1 = sb3[1], o2 = sb3[2];
#pragma unroll
        for (int q = 0; q < 16; ++q) {
            o0 = fmaf(h2[q], sW3[q * 3 + 0], o0);
            o1 = fmaf(h2[q], sW3[q * 3 + 1], o1);
            o2 = fmaf(h2[q], sW3[q * 3 + 2], o2);
        }
        out[3 * node + 0] = o0;
        out[3 * node + 1] = o1;
        out[3 * node + 2] = o2;
    }
}

// ---------------- fallback (global atomics) ----------------

__global__ __launch_bounds__(256) void edge_scatter_kernel(
    const int* __restrict__ rows, const int* __restrict__ cols,
    const float* __restrict__ x, float* __restrict__ agg, int n_edges)
{
    const long long tid = (long long)blockIdx.x * blockDim.x + threadIdx.x;
    const long long stride = (long long)gridDim.x * blockDim.x;
    for (long long i = tid; i < n_edges; i += stride) {
        int r = rows[i], c = cols[i];
        const float* xs = x + 3ll * r; float* a = agg + 3ll * c;
        atomicAdd(a + 0, xs[0]); atomicAdd(a + 1, xs[1]); atomicAdd(a + 2, xs[2]);
    }
}

__global__ __launch_bounds__(256) void node_mlp_kernel(
    const float* __restrict__ x,
    const float* __restrict__ W1, const float* __restrict__ b1,
    const float* __restrict__ W2, const float* __restrict__ b2,
    const float* __restrict__ W3, const float* __restrict__ b3,
    float* __restrict__ out, int n_nodes)
{
    __shared__ float sW1[96], sb1[16], sW2[256], sb2[16], sW3[48], sb3[3];
    const int t = threadIdx.x;
    if (t < 96)  sW1[t] = W1[t];
    if (t < 16)  sb1[t] = b1[t];
    sW2[t] = W2[t];
    if (t < 16)  sb2[t] = b2[t];
    if (t < 48)  sW3[t] = W3[t];
    if (t < 3)   sb3[t] = b3[t];
    __syncthreads();

    const int i = blockIdx.x * 256 + t;
    if (i >= n_nodes) return;

    float in6[6];
    in6[0] = x[3 * i + 0];
    in6[1] = x[3 * i + 1];
    in6[2] = x[3 * i + 2];
    in6[3] = out[3 * i + 0];
    in6[4] = out[3 * i + 1];
    in6[5] = out[3 * i + 2];

    float h1[16];
#pragma unroll
    for (int j = 0; j < 16; ++j) {
        float s = sb1[j];
#pragma unroll
        for (int k = 0; k < 6; ++k) s = fmaf(in6[k], sW1[k * 16 + j], s);
        h1[j] = fmaxf(s, 0.0f);
    }
    float h2[16];
#pragma unroll
    for (int j = 0; j < 16; ++j) {
        float s = sb2[j];
#pragma unroll
        for (int k = 0; k < 16; ++k) s = fmaf(h1[k], sW2[k * 16 + j], s);
        h2[j] = fmaxf(s, 0.0f);
    }
    float o[3];
#pragma unroll
    for (int c = 0; c < 3; ++c) {
        float s = sb3[c];
#pragma unroll
        for (int j = 0; j < 16; ++j) s = fmaf(h2[j], sW3[j * 3 + c], s);
        o[c] = s;
    }
    out[3 * i + 0] = o[0];
    out[3 * i + 1] = o[1];
    out[3 * i + 2] = o[2];
}

extern "C" void kernel_launch(void* const* d_in, const int* in_sizes, int n_in,
                              void* d_out, int out_size, void* d_ws, size_t ws_size,
                              hipStream_t stream) {
    const float* x   = (const float*)d_in[0];
    const int*   ei  = (const int*)d_in[1];   // [2, E] int32
    const float* W1  = (const float*)d_in[5];
    const float* b1  = (const float*)d_in[6];
    const float* W2  = (const float*)d_in[7];
    const float* b2  = (const float*)d_in[8];
    const float* W3  = (const float*)d_in[9];
    const float* b3  = (const float*)d_in[10];

    const int n_nodes = in_sizes[0] / 3;
    const int n_edges = in_sizes[1] / 2;
    const int* rows = ei;            // edge_index[0]
    const int* cols = ei + n_edges;  // edge_index[1]
    float* out = (float*)d_out;

    const int nb = (n_nodes + BSIZE - 1) >> CSHIFT;   // col-buckets (245)

    // ws layout: packed[E] u32 | hist[NBLK*nb] i32 | keyTotal[nb] | keyStart[nb+1]
    const size_t need = (size_t)n_edges * 4 + (size_t)NBLK * nb * 4
                      + (size_t)nb * 4 + (size_t)(nb + 1) * 4;
    const bool fast = (ws_size >= need) && (nb <= MAXNB)
                   && (n_nodes <= (1 << 20));   // (row<<12)|local fits u32

    if (fast) {
        unsigned* packed = (unsigned*)d_ws;
        int* hist        = (int*)(packed + n_edges);
        int* keyTotal    = hist + (size_t)NBLK * nb;
        int* keyStart    = keyTotal + nb;

        int chunk = (n_edges + NBLK - 1) / NBLK;
        chunk = (chunk + 3) & ~3;    // keep per-block int4 loads 16B-aligned

        hist_kernel<<<NBLK, HS_THREADS, 0, stream>>>(cols, hist, nb, chunk, n_edges);
        scan_blocks_kernel<<<nb, NBLK, 0, stream>>>(hist, keyTotal, nb);
        scan_keys_kernel<<<1, 1024, 0, stream>>>(keyTotal, keyStart, nb);
        scatter_kernel<<<NBLK, HS_THREADS, 0, stream>>>(rows, cols, hist, keyStart,
                                                        packed, nb, chunk, n_edges);
        bucket_agg_mlp_kernel<<<nb, AGG_THREADS, 0, stream>>>(
            packed, x, keyStart, W1, b1, W2, b2, W3, b3, out, n_nodes);
    } else {
        hipMemsetAsync(d_out, 0, (size_t)out_size * sizeof(float), stream);
        edge_scatter_kernel<<<8192, 256, 0, stream>>>(rows, cols, x, out, n_edges);
        const int nblocks = (n_nodes + 255) / 256;
        node_mlp_kernel<<<nblocks, 256, 0, stream>>>(x, W1, b1, W2, b2, W3, b3, out, n_nodes);
    }
}